// Round 3
// baseline (518.062 us; speedup 1.0000x reference)
//
#include <hip/hip_runtime.h>
#include <math.h>

#define BATCH 16
#define NHEAD 32
#define HDIM 128
#define HIDDEN 4096
#define BS 16
#define MB 128
#define EPS 1e-6f
#define CHUNK 8     // tokens per block (half a KV page)
#define SPLIT 256   // max chunks per sequence (MB*BS/CHUNK)

typedef float floatx4 __attribute__((ext_vector_type(4)));  // native vec: OK for nontemporal

// ws layout (floats):
//   pm:   [B][H][SPLIT]            at 0
//   pl:   [B][H][SPLIT]            at PL_OFF
//   pacc: [B][H][SPLIT][HDIM]      at PA_OFF
#define PCOUNT (BATCH * NHEAD * SPLIT)
#define PL_OFF PCOUNT
#define PA_OFF (2 * PCOUNT)

// Load one 16 KB token row (all 32 heads) into 8 float4-regs per thread.
// Thread t, sub-iter i covers float4 slot t+256i => head = (t>>5) + 8i, dims 4*lane..
#define LOADKV(KA, VA, T)                                                       \
    do {                                                                        \
        const floatx4* kr_ = kbp + (size_t)(T) * (HIDDEN / 4);                  \
        const floatx4* vr_ = vbp + (size_t)(T) * (HIDDEN / 4);                  \
        _Pragma("unroll") for (int i_ = 0; i_ < 4; i_++) {                      \
            KA[i_] = __builtin_nontemporal_load(&kr_[tid + 256 * i_]);          \
            VA[i_] = __builtin_nontemporal_load(&vr_[tid + 256 * i_]);          \
        }                                                                       \
    } while (0)

// Online-softmax update for the 4 head-chains this thread owns.
#define COMPUTE(KA, VA)                                                         \
    do {                                                                        \
        _Pragma("unroll") for (int i_ = 0; i_ < 4; i_++) {                      \
            float d_ = KA[i_][0] * qf[i_][0] + KA[i_][1] * qf[i_][1] +          \
                       KA[i_][2] * qf[i_][2] + KA[i_][3] * qf[i_][3];           \
            _Pragma("unroll") for (int msk_ = 16; msk_ >= 1; msk_ >>= 1)        \
                d_ += __shfl_xor(d_, msk_, 64);                                 \
            float sc_ = d_ * 0.08838834764831845f;                              \
            float mn_ = fmaxf(m0[i_], sc_);                                     \
            float al_ = __expf(m0[i_] - mn_);                                   \
            float p_ = __expf(sc_ - mn_);                                       \
            l0[i_] = l0[i_] * al_ + p_;                                         \
            acc[i_] = acc[i_] * al_ + p_ * VA[i_];                              \
            m0[i_] = mn_;                                                       \
        }                                                                       \
    } while (0)

// One block = one (batch, 8-token chunk). Streams 128 KB K + 128 KB V
// contiguously, all 32 heads, software-pipelined (dbuf regs) token loop.
__global__ __launch_bounds__(256, 4) void attn_page_kernel(
    const float* __restrict__ x, const float* __restrict__ rw,
    const float* __restrict__ kc, const float* __restrict__ vc,
    const int* __restrict__ bt, const int* __restrict__ cl,
    float* __restrict__ pm, float* __restrict__ pl, float* __restrict__ pacc) {
    const int si = blockIdx.x;  // chunk index within sequence
    const int b = blockIdx.y;
    const int L = cl[b];
    const int nsp = (L + CHUNK - 1) >> 3;
    if (si >= nsp) return;  // uniform early-exit (before any barrier)
    const int nt = min(CHUNK, L - (si << 3));
    const int tid = threadIdx.x;
    const int hw = tid >> 5;
    const int lane = tid & 31;

    // ---- inline RMSNorm: q fragments for float4 slots tid + 256*i (L2-hot) ----
    const floatx4* xr = (const floatx4*)(x + (size_t)b * HIDDEN);
    const floatx4* wr = (const floatx4*)rw;
    floatx4 qf[4];
    float ss = 0.f;
#pragma unroll
    for (int i = 0; i < 4; i++) {
        floatx4 v = xr[tid + 256 * i];
        qf[i] = v;
        ss += v[0] * v[0] + v[1] * v[1] + v[2] * v[2] + v[3] * v[3];
    }
#pragma unroll
    for (int m = 32; m >= 1; m >>= 1) ss += __shfl_xor(ss, m, 64);
    __shared__ float red[4];
    if ((tid & 63) == 0) red[tid >> 6] = ss;
    __syncthreads();
    const float rstd = rsqrtf((red[0] + red[1] + red[2] + red[3]) * (1.0f / HIDDEN) + EPS);
#pragma unroll
    for (int i = 0; i < 4; i++) {
        floatx4 wv = wr[tid + 256 * i];
        qf[i] *= rstd * wv;
    }

    const int pg = bt[b * MB + (si >> 1)];  // wave-uniform
    const int t0 = (si & 1) * CHUNK;        // token offset within page
    const floatx4* kbp = (const floatx4*)(kc + (size_t)pg * (BS * HIDDEN)) +
                         (size_t)t0 * (HIDDEN / 4);
    const floatx4* vbp = (const floatx4*)(vc + (size_t)pg * (BS * HIDDEN)) +
                         (size_t)t0 * (HIDDEN / 4);

    float m0[4], l0[4];
    floatx4 acc[4];
#pragma unroll
    for (int i = 0; i < 4; i++) {
        m0[i] = -INFINITY;
        l0[i] = 0.f;
        acc[i] = (floatx4)(0.f);
    }

    if (nt == CHUNK) {
        // common case: fully unrolled, double-buffered (loads for t+1 in flight
        // while computing t — HBM latency hides under the shfl/exp chain)
        floatx4 kA[4], vA[4], kB[4], vB[4];
        LOADKV(kA, vA, 0);
#pragma unroll
        for (int t = 0; t < CHUNK; t += 2) {
            LOADKV(kB, vB, t + 1);
            COMPUTE(kA, vA);
            if (t + 2 < CHUNK) LOADKV(kA, vA, t + 2);
            COMPUTE(kB, vB);
        }
    } else {
        // rare tail chunk (at most one per sequence)
        for (int t = 0; t < nt; ++t) {
            floatx4 k4[4], v4[4];
            LOADKV(k4, v4, t);
            COMPUTE(k4, v4);
        }
    }

    // ---- write partials: head h = hw + 8*i; coalesced float4 per half-wave ----
#pragma unroll
    for (int i = 0; i < 4; i++) {
        const int h = hw + 8 * i;
        const size_t pb = (size_t)(b * NHEAD + h) * SPLIT + si;
        if (lane == 0) {
            pm[pb] = m0[i];
            pl[pb] = l0[i];
        }
        *(floatx4*)(pacc + pb * HDIM + 4 * lane) = acc[i];
    }
}

// ---- combine: parallel (coalesced) partial-stat load, LDS-staged weights ----
__global__ __launch_bounds__(128) void attn_combine_kernel(
    const float* __restrict__ pm, const float* __restrict__ pl,
    const float* __restrict__ pacc, const float* __restrict__ resid,
    const int* __restrict__ cl, float* __restrict__ out) {
    const int h = blockIdx.x;
    const int b = blockIdx.y;
    const int tid = threadIdx.x;
    const int L = cl[b];
    const int nsp = (L + CHUNK - 1) >> 3;
    const size_t pb0 = (size_t)(b * NHEAD + h) * SPLIT;

    __shared__ float s_w[SPLIT];
    __shared__ float s_red[2];
    __shared__ float s_red2[2];

    // each thread owns split slots {tid, tid+128}; loads are coalesced
    const float m0v = (tid < nsp) ? pm[pb0 + tid] : -INFINITY;
    const float m1v = (tid + 128 < nsp) ? pm[pb0 + tid + 128] : -INFINITY;
    float mx = fmaxf(m0v, m1v);
#pragma unroll
    for (int msk = 32; msk >= 1; msk >>= 1) mx = fmaxf(mx, __shfl_xor(mx, msk, 64));
    if ((tid & 63) == 0) s_red[tid >> 6] = mx;
    __syncthreads();
    const float M = fmaxf(s_red[0], s_red[1]);

    float lsum = 0.f;
    if (tid < nsp) {
        float w = __expf(m0v - M);
        s_w[tid] = w;
        lsum += pl[pb0 + tid] * w;
    }
    if (tid + 128 < nsp) {
        float w = __expf(m1v - M);
        s_w[tid + 128] = w;
        lsum += pl[pb0 + tid + 128] * w;
    }
#pragma unroll
    for (int msk = 32; msk >= 1; msk >>= 1) lsum += __shfl_xor(lsum, msk, 64);
    if ((tid & 63) == 0) s_red2[tid >> 6] = lsum;
    __syncthreads();  // also publishes s_w
    const float Ls = s_red2[0] + s_red2[1];

    // accumulate: thread tid owns output dim tid; pacc rows are 512 B coalesced
    float A = 0.f;
    const float* pa = pacc + pb0 * HDIM + tid;
    int si = 0;
    for (; si + 4 <= nsp; si += 4) {
        A += s_w[si] * pa[(size_t)si * HDIM] + s_w[si + 1] * pa[(size_t)(si + 1) * HDIM] +
             s_w[si + 2] * pa[(size_t)(si + 2) * HDIM] +
             s_w[si + 3] * pa[(size_t)(si + 3) * HDIM];
    }
    for (; si < nsp; ++si) A += s_w[si] * pa[(size_t)si * HDIM];

    const size_t oi = (size_t)b * HIDDEN + h * HDIM + tid;
    out[oi] = resid[oi] + A / Ls;
}

extern "C" void kernel_launch(void* const* d_in, const int* in_sizes, int n_in,
                              void* d_out, int out_size, void* d_ws, size_t ws_size,
                              hipStream_t stream) {
    const float* hs = (const float*)d_in[0];
    const float* kc = (const float*)d_in[1];
    const float* vc = (const float*)d_in[2];
    const int* bt = (const int*)d_in[3];
    const int* cl = (const int*)d_in[4];
    const float* rw = (const float*)d_in[5];
    float* out = (float*)d_out;
    float* ws = (float*)d_ws;
    float* pm = ws;
    float* pl = ws + PL_OFF;
    float* pacc = ws + PA_OFF;

    attn_page_kernel<<<dim3(SPLIT, BATCH), 256, 0, stream>>>(hs, rw, kc, vc, bt, cl,
                                                             pm, pl, pacc);
    attn_combine_kernel<<<dim3(NHEAD, BATCH), 128, 0, stream>>>(pm, pl, pacc, hs, cl, out);
}